// Round 4
// baseline (308.002 us; speedup 1.0000x reference)
//
#include <hip/hip_runtime.h>

#define E_EDGES 32768
#define NN 8192
#define HID 128

typedef _Float16 half8 __attribute__((ext_vector_type(8)));
typedef _Float16 half4 __attribute__((ext_vector_type(4)));
typedef float f32x4 __attribute__((ext_vector_type(4)));

// ------- W2 -> f16 B-matrix, MFMA-fragment-linear layout -------------------
// k<128*CI theta rows (k=h*CI+i), next CI rows = b2 (he==1), zero to Kpad.
// out[((k>>3)*CO + n)*8 + (k&7)]: one lane's b-frag = contiguous 16B.
__device__ __forceinline__ void prep_one(int idx, int l2ci, int l2co,
                                         const float* __restrict__ W2,
                                         const float* __restrict__ b2,
                                         _Float16* __restrict__ out) {
  int CI = 1 << l2ci, CO = 1 << l2co;
  int Kmain = CI << 7;
  int j = idx & 7;
  int n = (idx >> 3) & (CO - 1);
  int kg = idx >> (3 + l2co);
  int k = kg * 8 + j;
  float v = 0.f;
  if (k < Kmain) {
    int hh = k >> l2ci, i = k & (CI - 1);
    v = W2[((hh << l2ci) + i) * CO + n];
  } else if (k < Kmain + CI) {
    v = b2[(k - Kmain) * CO + n];
  }
  out[idx] = (_Float16)v;
}

#define ZTOT (8192 * 32 + 8192 * 64 + 8192 * 64 + 512 * 64)
#define PREP0 (2176 * 32)
#define PREP1 (4224 * 64)
#define PREP2 (8320 * 64)

// ------- prep: zero agg1/agg2/agg3/ssum (contiguous) + build B matrices ----
__global__ void prep_k(float* __restrict__ zr,
                       const float* __restrict__ W2a, const float* __restrict__ b2a, _Float16* __restrict__ oa,
                       const float* __restrict__ W2b, const float* __restrict__ b2b, _Float16* __restrict__ ob,
                       const float* __restrict__ W2c, const float* __restrict__ b2c, _Float16* __restrict__ oc) {
  int idx = blockIdx.x * 256 + threadIdx.x;
  if (idx < ZTOT) { zr[idx] = 0.f; return; }
  idx -= ZTOT;
  if (idx < PREP0) prep_one(idx, 4, 5, W2a, b2a, oa);
  else if (idx < PREP0 + PREP1) prep_one(idx - PREP0, 5, 6, W2b, b2b, ob);
  else if (idx < PREP0 + PREP1 + PREP2) prep_one(idx - PREP0 - PREP1, 6, 6, W2c, b2c, oc);
}

// ------- main fused kernel: edge MLP1 + Z@W2r GEMM (split-K=4) -------------
// Barrier-free K-loop (A in registers, B streamed from L2 with depth-4
// register prefetch); epilogue scatters msg partials straight into dense
// agg[n][CO] via atomicAdd (L2-resident, low contention) -- no msgbuf.
template <int CI, int CO>
__launch_bounds__(256, 2)
__global__ void msg_mfma_k(const float* __restrict__ xcur, const int* __restrict__ src,
                           const int* __restrict__ dst, const float* __restrict__ eattr,
                           const float* __restrict__ W1, const float* __restrict__ b1,
                           const _Float16* __restrict__ Bsw, float* __restrict__ agg) {
  constexpr int ME = 256;                      // edges per block
  constexpr int L2CI = (CI == 64) ? 6 : ((CI == 32) ? 5 : 4);
  constexpr int Kmain = 128 * CI;
  constexpr int SPLITK = 32 * CI;              // k per split (splits 0..2)
  constexpr int TAILK = ((SPLITK + CI + 127) / 128) * 128;
  constexpr int XSTR = CI + 8;
  constexpr int FC = CO / 16;
  constexpr int C4 = CI / 4;
  constexpr int L2C4 = L2CI - 2;
  constexpr int NV = (CI == 64) ? 2 : 1;       // x-fragment variants per lane

  __shared__ _Float16 he_s[32 * ME];           // [h-local(32)][e]
  __shared__ _Float16 xs_s[ME * XSTR];         // [e][i]
  __shared__ float ea_s[ME * 5];
  __shared__ float W1s[5 * 32];
  __shared__ float b1s[32];
  __shared__ int src_s[ME];
  __shared__ int dst_s[ME];

  int t = threadIdx.x;
  int e0 = blockIdx.x * ME;
  int y = blockIdx.y;                          // split: h in [32y, 32y+32)
  int hbeg = y * 32;

  for (int j = t; j < ME * 5; j += 256) ea_s[j] = eattr[e0 * 5 + j];
  if (t < 5 * 32) W1s[t] = W1[(t >> 5) * HID + hbeg + (t & 31)];
  if (t < 32) b1s[t] = b1[hbeg + t];
  src_s[t] = src[e0 + t];
  dst_s[t] = dst[e0 + t];
  __syncthreads();

  for (int j = t; j < 32 * ME; j += 256) {
    int hl = j >> 8, e = j & (ME - 1);
    float v = b1s[hl];
#pragma unroll
    for (int d = 0; d < 5; ++d) v += ea_s[e * 5 + d] * W1s[d * 32 + hl];
    he_s[hl * ME + e] = (_Float16)fmaxf(v, 0.f);
  }
  for (int j = t; j < ME * C4; j += 256) {
    int e = j >> L2C4, i4 = j & (C4 - 1);
    float4 v = ((const float4*)xcur)[src_s[e] * C4 + i4];
    half4 hq = {(_Float16)v.x, (_Float16)v.y, (_Float16)v.z, (_Float16)v.w};
    *(half4*)&xs_s[e * XSTR + i4 * 4] = hq;
  }
  __syncthreads();                             // last barrier

  int lane = t & 63;
  int w = t >> 6;
  int quad = lane >> 4, l15 = lane & 15;

  // loop-invariant per-lane A-side x fragments -> registers
  half8 xreg[4][NV];
#pragma unroll
  for (int fr = 0; fr < 4; ++fr)
#pragma unroll
    for (int v = 0; v < NV; ++v)
      xreg[fr][v] = *(const half8*)&xs_s[(w * 64 + fr * 16 + l15) * XSTR +
                                         ((quad * 8 + v * 32) & (CI - 1))];

  int cbeg = y * (SPLITK / 32);
  int cend = cbeg + ((y < 3) ? (SPLITK / 32) : (TAILK / 32));
  int nrounds = (cend - cbeg) >> 2;

  const half8* bsw8 = (const half8*)Bsw;
  int ib = quad * CO + l15;

  f32x4 acc[4][FC];
#pragma unroll
  for (int fr = 0; fr < 4; ++fr)
#pragma unroll
    for (int fc = 0; fc < FC; ++fc)
#pragma unroll
      for (int r = 0; r < 4; ++r) acc[fr][fc][r] = 0.f;

  half8 breg[4][FC];
#pragma unroll
  for (int j = 0; j < 4; ++j)
#pragma unroll
    for (int fc = 0; fc < FC; ++fc)
      breg[j][fc] = bsw8[(cbeg + j) * 4 * CO + ib + fc * 16];

  for (int r = 0; r < nrounds; ++r) {
#pragma unroll
    for (int j = 0; j < 4; ++j) {
      int c = cbeg + r * 4 + j;
      int kq = c * 32 + quad * 8;
      int hr = (kq < Kmain) ? ((kq >> L2CI) - hbeg) : 0;   // clamped (OOB-safe)
      constexpr int PAR = (CI == 64) ? 1 : 0;
      int vi = PAR ? (j & 1) : 0;
      half8 a[4];
#pragma unroll
      for (int fr = 0; fr < 4; ++fr) {
        int e = w * 64 + fr * 16 + l15;
        _Float16 hv = (kq < Kmain) ? he_s[hr * ME + e] : (_Float16)1.f;
        a[fr] = xreg[fr][vi] * hv;
      }
#pragma unroll
      for (int fc = 0; fc < FC; ++fc) {
#pragma unroll
        for (int fr = 0; fr < 4; ++fr)
          acc[fr][fc] = __builtin_amdgcn_mfma_f32_16x16x32_f16(a[fr], breg[j][fc], acc[fr][fc], 0, 0, 0);
      }
      int cn = c + 4;
      if (cn >= cend) cn = cend - 1;           // clamped branch-free prefetch
#pragma unroll
      for (int fc = 0; fc < FC; ++fc)
        breg[j][fc] = bsw8[cn * 4 * CO + ib + fc * 16];
    }
  }

  // epilogue: scatter partials into agg via atomics.
  // C/D layout: row(e_local)=quad*4+r, col(o)=l15. Per instr: 4 segments x 64B.
#pragma unroll
  for (int fr = 0; fr < 4; ++fr)
#pragma unroll
    for (int r = 0; r < 4; ++r) {
      int el = w * 64 + fr * 16 + quad * 4 + r;
      int d = dst_s[el];                       // broadcast within quad
      float* base = agg + (size_t)d * CO + l15;
#pragma unroll
      for (int fc = 0; fc < FC; ++fc)
        atomicAdd(base + fc * 16, acc[fr][fc][r]);
    }
}

// ------- finish: ELU(agg + x@root + bias); last layer fuses subgraph pool --
template <int CI, int CO, bool POOL>
__global__ void fin_k(const float* __restrict__ xcur, const float* __restrict__ root,
                      const float* __restrict__ bias, const float* __restrict__ agg,
                      const int* __restrict__ n2s, float* __restrict__ ssum,
                      float* __restrict__ xnext) {
  constexpr int NB = 256 / CO;
  __shared__ float xs[NB * CI];
  int t = threadIdx.x;
  int n0 = blockIdx.x * NB;
  for (int j = t; j < NB * CI; j += 256) xs[j] = xcur[n0 * CI + j];
  __syncthreads();
  int nl = t / CO, o = t & (CO - 1);
  int n = n0 + nl;
  float a = bias[o] + agg[n * CO + o];
#pragma unroll
  for (int i = 0; i < CI; ++i) a += xs[nl * CI + i] * root[i * CO + o];
  float r = a > 0.f ? a : expm1f(a);
  if (POOL) atomicAdd(&ssum[(n2s[n] << 6) + o], r);
  else xnext[n * CO + o] = r;
}

// ------- final: graph pool (counts via binary search on sorted segs) + head
__device__ __forceinline__ int lbound(const int* __restrict__ a, int n, int v) {
  int lo = 0, hi = n;
  while (lo < hi) { int m = (lo + hi) >> 1; if (a[m] < v) lo = m + 1; else hi = m; }
  return lo;
}

__global__ void final_k(const float* __restrict__ ssum, const int* __restrict__ n2s,
                        const int* __restrict__ s2g,
                        const float* __restrict__ w1, const float* __restrict__ b1,
                        const float* __restrict__ w2, const float* __restrict__ b2,
                        const float* __restrict__ w3, const float* __restrict__ b3,
                        float* __restrict__ out) {
  __shared__ float gsum[32 * 64];
  __shared__ float cnt_s[512];
  __shared__ float gcnt[32];
  __shared__ float s1[32 * 32];
  __shared__ float s2[32 * 16];
  int t = threadIdx.x;                         // 1024 threads
  for (int j = t; j < 32 * 64; j += 1024) gsum[j] = 0.f;
  if (t < 512) cnt_s[t] = (float)(lbound(n2s, NN, t + 1) - lbound(n2s, NN, t));
  if (t < 32) gcnt[t] = (float)(lbound(s2g, 512, t + 1) - lbound(s2g, 512, t));
  __syncthreads();
  for (int j = t; j < 512 * 64; j += 1024) {
    int s = j >> 6, o = j & 63;
    float v = ssum[j] / fmaxf(cnt_s[s], 1.f);
    atomicAdd(&gsum[(s2g[s] << 6) + o], v);
  }
  __syncthreads();
  for (int j = t; j < 2048; j += 1024) gsum[j] /= fmaxf(gcnt[j >> 6], 1.f);
  __syncthreads();
  {
    int g = t >> 5, jj = t & 31;               // 32 graphs x 32 cols = 1024
    float a = b1[jj];
    for (int i = 0; i < 64; ++i) a += gsum[(g << 6) + i] * w1[i * 32 + jj];
    s1[(g << 5) + jj] = a > 0.f ? a : expm1f(a);
  }
  __syncthreads();
  if (t < 512) {
    int g = t >> 4, jj = t & 15;
    float a = b2[jj];
    for (int i = 0; i < 32; ++i) a += s1[(g << 5) + i] * w2[i * 16 + jj];
    s2[(g << 4) + jj] = a > 0.f ? a : expm1f(a);
  }
  __syncthreads();
  if (t < 32) {
    float a = b3[0];
    for (int i = 0; i < 16; ++i) a += s2[(t << 4) + i] * w3[i];
    out[t] = a;
  }
}

extern "C" void kernel_launch(void* const* d_in, const int* in_sizes, int n_in,
                              void* d_out, int out_size, void* d_ws, size_t ws_size,
                              hipStream_t stream) {
  (void)in_sizes; (void)n_in; (void)out_size; (void)ws_size;
  const float* x0 = (const float*)d_in[0];
  const int* ei = (const int*)d_in[1];
  const float* ea = (const float*)d_in[2];
  const int* n2s = (const int*)d_in[3];
  const int* s2g = (const int*)d_in[4];
  const float* W1_[3] = {(const float*)d_in[5], (const float*)d_in[11], (const float*)d_in[17]};
  const float* b1_[3] = {(const float*)d_in[6], (const float*)d_in[12], (const float*)d_in[18]};
  const float* W2_[3] = {(const float*)d_in[7], (const float*)d_in[13], (const float*)d_in[19]};
  const float* b2_[3] = {(const float*)d_in[8], (const float*)d_in[14], (const float*)d_in[20]};
  const float* rt_[3] = {(const float*)d_in[9], (const float*)d_in[15], (const float*)d_in[21]};
  const float* bs_[3] = {(const float*)d_in[10], (const float*)d_in[16], (const float*)d_in[22]};
  const float* fc1w = (const float*)d_in[23]; const float* fc1b = (const float*)d_in[24];
  const float* fc2w = (const float*)d_in[25]; const float* fc2b = (const float*)d_in[26];
  const float* fc3w = (const float*)d_in[27]; const float* fc3b = (const float*)d_in[28];
  float* out = (float*)d_out;

  const int* srcp = ei;
  const int* dstp = ei + E_EDGES;

  char* wsb = (char*)d_ws;
  size_t off = 0;
  auto alloc = [&](size_t bytes) {
    void* p = wsb + off;
    off += (bytes + 255) & ~(size_t)255;
    return p;
  };
  _Float16* Bsw0 = (_Float16*)alloc((size_t)PREP0 * 2);
  _Float16* Bsw1 = (_Float16*)alloc((size_t)PREP1 * 2);
  _Float16* Bsw2 = (_Float16*)alloc((size_t)PREP2 * 2);
  // zero region: agg1 | agg2 | agg3 | ssum, contiguous (sizes all x256B)
  float* agg1 = (float*)alloc((size_t)NN * 32 * 4);
  float* agg2 = (float*)alloc((size_t)NN * 64 * 4);
  float* agg3 = (float*)alloc((size_t)NN * 64 * 4);
  float* ssum = (float*)alloc((size_t)512 * 64 * 4);
  float* x1 = (float*)alloc((size_t)NN * 32 * 4);
  float* x2 = (float*)alloc((size_t)NN * 64 * 4);

  const int preptot = ZTOT + PREP0 + PREP1 + PREP2;
  prep_k<<<(preptot + 255) / 256, 256, 0, stream>>>(agg1, W2_[0], b2_[0], Bsw0,
                                                    W2_[1], b2_[1], Bsw1,
                                                    W2_[2], b2_[2], Bsw2);

  dim3 mg(E_EDGES / 256, 4);
  msg_mfma_k<16, 32><<<mg, 256, 0, stream>>>(x0, srcp, dstp, ea, W1_[0], b1_[0], Bsw0, agg1);
  fin_k<16, 32, false><<<NN / 8, 256, 0, stream>>>(x0, rt_[0], bs_[0], agg1, n2s, ssum, x1);
  msg_mfma_k<32, 64><<<mg, 256, 0, stream>>>(x1, srcp, dstp, ea, W1_[1], b1_[1], Bsw1, agg2);
  fin_k<32, 64, false><<<NN / 4, 256, 0, stream>>>(x1, rt_[1], bs_[1], agg2, n2s, ssum, x2);
  msg_mfma_k<64, 64><<<mg, 256, 0, stream>>>(x2, srcp, dstp, ea, W1_[2], b1_[2], Bsw2, agg3);
  fin_k<64, 64, true><<<NN / 4, 256, 0, stream>>>(x2, rt_[2], bs_[2], agg3, n2s, ssum, nullptr);

  final_k<<<1, 1024, 0, stream>>>(ssum, n2s, s2g, fc1w, fc1b, fc2w, fc2b, fc3w, fc3b, out);
}

// Round 5
// 282.555 us; speedup vs baseline: 1.0901x; 1.0901x over previous
//
#include <hip/hip_runtime.h>

#define E_EDGES 32768
#define NN 8192
#define HID 128

typedef _Float16 half8 __attribute__((ext_vector_type(8)));
typedef _Float16 half4 __attribute__((ext_vector_type(4)));
typedef float f32x4 __attribute__((ext_vector_type(4)));

// ------- W2 -> f16 B-matrix, MFMA-fragment-linear layout -------------------
// k<128*CI theta rows (k=h*CI+i), next CI rows = b2 (he==1), zero to Kpad.
// out[((k>>3)*CO + n)*8 + (k&7)]: one lane's b-frag = contiguous 16B.
__device__ __forceinline__ void prep_one(int idx, int l2ci, int l2co,
                                         const float* __restrict__ W2,
                                         const float* __restrict__ b2,
                                         _Float16* __restrict__ out) {
  int CI = 1 << l2ci, CO = 1 << l2co;
  int Kmain = CI << 7;
  int j = idx & 7;
  int n = (idx >> 3) & (CO - 1);
  int kg = idx >> (3 + l2co);
  int k = kg * 8 + j;
  float v = 0.f;
  if (k < Kmain) {
    int hh = k >> l2ci, i = k & (CI - 1);
    v = W2[((hh << l2ci) + i) * CO + n];
  } else if (k < Kmain + CI) {
    v = b2[(k - Kmain) * CO + n];
  }
  out[idx] = (_Float16)v;
}

// zero region: agg1 | agg2 | agg3 | ssum | cnt_sub (contiguous, 256B-multiples)
#define ZTOT (8192 * 32 + 8192 * 64 + 8192 * 64 + 512 * 64 + 512)
#define PREP0 (2176 * 32)
#define PREP1 (4224 * 64)
#define PREP2 (8320 * 64)

__global__ void prep_k(float* __restrict__ zr,
                       const float* __restrict__ W2a, const float* __restrict__ b2a, _Float16* __restrict__ oa,
                       const float* __restrict__ W2b, const float* __restrict__ b2b, _Float16* __restrict__ ob,
                       const float* __restrict__ W2c, const float* __restrict__ b2c, _Float16* __restrict__ oc) {
  int idx = blockIdx.x * 256 + threadIdx.x;
  if (idx < ZTOT) { zr[idx] = 0.f; return; }
  idx -= ZTOT;
  if (idx < PREP0) prep_one(idx, 4, 5, W2a, b2a, oa);
  else if (idx < PREP0 + PREP1) prep_one(idx - PREP0, 5, 6, W2b, b2b, ob);
  else if (idx < PREP0 + PREP1 + PREP2) prep_one(idx - PREP0 - PREP1, 6, 6, W2c, b2c, oc);
}

// ------- main fused kernel: edge MLP1 + Z@W2r GEMM (split-K=4) -------------
// Barrier-free K-loop; A-side x in registers; he read as b128 VECTORS from a
// TRANSPOSED LDS tile (one read per fr per 8-h window, static extraction in
// the unrolled window body) -- kills the ds_read_u16 storm that capped
// MfmaUtil at 21.6%. B streamed from L2 with depth-4 register prefetch.
// Epilogue scatters partials into dense agg[n][CO] via atomicAdd.
template <int CI, int CO>
__launch_bounds__(256, 2)
__global__ void msg_mfma_k(const float* __restrict__ xcur, const int* __restrict__ src,
                           const int* __restrict__ dst, const float* __restrict__ eattr,
                           const float* __restrict__ W1, const float* __restrict__ b1,
                           const _Float16* __restrict__ Bsw, float* __restrict__ agg) {
  constexpr int ME = 256;                      // edges per block
  constexpr int L2CI = (CI == 64) ? 6 : ((CI == 32) ? 5 : 4);
  constexpr int XSTR = CI + 8;
  constexpr int FC = CO / 16;
  constexpr int C4 = CI / 4;
  constexpr int L2C4 = L2CI - 2;
  constexpr int NV = (CI == 64) ? 2 : 1;       // x-fragment variants per lane
  constexpr int HS = 40;                       // he_t stride (16B-aligned reads)
  constexpr int CW = CI / 4;                   // chunks per 8-h window
  constexpr int RR = CW / 4;                   // rounds-of-4 per window

  __shared__ _Float16 he_t[ME * HS];           // [e][h-local(32)] transposed
  __shared__ _Float16 xs_s[ME * XSTR];         // [e][i]
  __shared__ float ea_s[ME * 5];
  __shared__ float W1s[5 * 32];
  __shared__ float b1s[32];
  __shared__ int src_s[ME];
  __shared__ int dst_s[ME];

  int t = threadIdx.x;
  int e0 = blockIdx.x * ME;
  int y = blockIdx.y;                          // split: h in [32y, 32y+32)
  int hbeg = y * 32;

  for (int j = t; j < ME * 5; j += 256) ea_s[j] = eattr[e0 * 5 + j];
  if (t < 5 * 32) W1s[t] = W1[(t >> 5) * HID + hbeg + (t & 31)];
  if (t < 32) b1s[t] = b1[hbeg + t];
  src_s[t] = src[e0 + t];
  dst_s[t] = dst[e0 + t];
  __syncthreads();

  // edge MLP1 (this split's 32 h), written TRANSPOSED
  for (int j = t; j < 32 * ME; j += 256) {
    int hl = j >> 8, e = j & (ME - 1);
    float v = b1s[hl];
#pragma unroll
    for (int d = 0; d < 5; ++d) v += ea_s[e * 5 + d] * W1s[d * 32 + hl];
    he_t[e * HS + hl] = (_Float16)fmaxf(v, 0.f);
  }
  for (int j = t; j < ME * C4; j += 256) {
    int e = j >> L2C4, i4 = j & (C4 - 1);
    float4 v = ((const float4*)xcur)[src_s[e] * C4 + i4];
    half4 hq = {(_Float16)v.x, (_Float16)v.y, (_Float16)v.z, (_Float16)v.w};
    *(half4*)&xs_s[e * XSTR + i4 * 4] = hq;
  }
  __syncthreads();                             // last barrier

  int lane = t & 63;
  int w = t >> 6;
  int quad = lane >> 4, l15 = lane & 15;

  // loop-invariant per-lane A-side x fragments -> registers
  half8 xreg[4][NV];
#pragma unroll
  for (int fr = 0; fr < 4; ++fr)
#pragma unroll
    for (int v = 0; v < NV; ++v)
      xreg[fr][v] = *(const half8*)&xs_s[(w * 64 + fr * 16 + l15) * XSTR +
                                         ((quad * 8 + v * 32) & (CI - 1))];

  int cbeg = y * CI;                           // chunks per split = CI
  int ctail_end = cbeg + CI + ((y == 3) ? 4 : 0);

  const half8* bsw8 = (const half8*)Bsw;
  int ib = quad * CO + l15;

  f32x4 acc[4][FC];
#pragma unroll
  for (int fr = 0; fr < 4; ++fr)
#pragma unroll
    for (int fc = 0; fc < FC; ++fc)
#pragma unroll
      for (int r = 0; r < 4; ++r) acc[fr][fc][r] = 0.f;

  half8 breg[4][FC];
#pragma unroll
  for (int j = 0; j < 4; ++j)
#pragma unroll
    for (int fc = 0; fc < FC; ++fc)
      breg[j][fc] = bsw8[(cbeg + j) * 4 * CO + ib + fc * 16];

  for (int win = 0; win < 4; ++win) {
    half8 hreg[4];
#pragma unroll
    for (int fr = 0; fr < 4; ++fr)
      hreg[fr] = *(const half8*)&he_t[(w * 64 + fr * 16 + l15) * HS + win * 8];
#pragma unroll
    for (int rr = 0; rr < RR; ++rr) {
#pragma unroll
      for (int j = 0; j < 4; ++j) {
        int cl = win * CW + rr * 4 + j;        // chunk-local 0..CI-1
        int c = cbeg + cl;
        constexpr int PAR = (CI == 64) ? 1 : 0;
        int vi = PAR ? (cl & 1) : 0;
        half8 a[4];
#pragma unroll
        for (int fr = 0; fr < 4; ++fr) {
          _Float16 hv;
          if (CI == 16)      hv = (quad & 2) ? hreg[fr][2 * j + 1] : hreg[fr][2 * j];
          else if (CI == 32) hv = hreg[fr][rr * 4 + j];
          else               hv = hreg[fr][(rr * 4 + j) >> 1];
          half8 hb = {hv, hv, hv, hv, hv, hv, hv, hv};
          a[fr] = xreg[fr][vi] * hb;
        }
#pragma unroll
        for (int fc = 0; fc < FC; ++fc) {
#pragma unroll
          for (int fr = 0; fr < 4; ++fr)
            acc[fr][fc] = __builtin_amdgcn_mfma_f32_16x16x32_f16(a[fr], breg[cl & 3][fc], acc[fr][fc], 0, 0, 0);
        }
        int cn = c + 4;
        if (cn >= ctail_end) cn = ctail_end - 1;  // clamped branch-free prefetch
#pragma unroll
        for (int fc = 0; fc < FC; ++fc)
          breg[cl & 3][fc] = bsw8[cn * 4 * CO + ib + fc * 16];
      }
    }
  }

  // b2 tail (4 chunks, he == 1), only on split 3
  if (y == 3) {
#pragma unroll
    for (int j = 0; j < 4; ++j) {
      int cl = CI + j;
      constexpr int PAR = (CI == 64) ? 1 : 0;
      int vi = PAR ? (cl & 1) : 0;
#pragma unroll
      for (int fc = 0; fc < FC; ++fc) {
#pragma unroll
        for (int fr = 0; fr < 4; ++fr)
          acc[fr][fc] = __builtin_amdgcn_mfma_f32_16x16x32_f16(xreg[fr][vi], breg[cl & 3][fc], acc[fr][fc], 0, 0, 0);
      }
    }
  }

  // epilogue: scatter partials into agg via device atomics.
  // C/D layout: row(e_local)=quad*4+r, col(o)=l15.
#pragma unroll
  for (int fr = 0; fr < 4; ++fr)
#pragma unroll
    for (int r = 0; r < 4; ++r) {
      int el = w * 64 + fr * 16 + quad * 4 + r;
      int d = dst_s[el];
      float* base = agg + (size_t)d * CO + l15;
#pragma unroll
      for (int fc = 0; fc < FC; ++fc)
        atomicAdd(base + fc * 16, acc[fr][fc][r]);
    }
}

// ------- finish: ELU(agg + x@root + bias); fin1 counts, fin3 pools ---------
template <int CI, int CO, bool POOL, bool CNT>
__global__ void fin_k(const float* __restrict__ xcur, const float* __restrict__ root,
                      const float* __restrict__ bias, const float* __restrict__ agg,
                      const int* __restrict__ n2s, int* __restrict__ cnt_sub,
                      float* __restrict__ ssum, float* __restrict__ xnext) {
  constexpr int NB = 256 / CO;
  __shared__ float xs[NB * CI];
  int t = threadIdx.x;
  int n0 = blockIdx.x * NB;
  for (int j = t; j < NB * CI; j += 256) xs[j] = xcur[n0 * CI + j];
  __syncthreads();
  int nl = t / CO, o = t & (CO - 1);
  int n = n0 + nl;
  float a = bias[o] + agg[n * CO + o];
#pragma unroll
  for (int i = 0; i < CI; ++i) a += xs[nl * CI + i] * root[i * CO + o];
  float r = a > 0.f ? a : expm1f(a);
  if (CNT && o == 0) atomicAdd(&cnt_sub[n2s[n]], 1);
  if (POOL) atomicAdd(&ssum[(n2s[n] << 6) + o], r);
  else xnext[n * CO + o] = r;
}

// ------- head: per-graph pool (32 blocks x 64 thr) + MLP -------------------
__device__ __forceinline__ int lbound(const int* __restrict__ a, int n, int v) {
  int lo = 0, hi = n;
  while (lo < hi) { int m = (lo + hi) >> 1; if (a[m] < v) lo = m + 1; else hi = m; }
  return lo;
}

__global__ void head_k(const float* __restrict__ ssum, const int* __restrict__ cnt_sub,
                       const int* __restrict__ s2g,
                       const float* __restrict__ w1, const float* __restrict__ b1,
                       const float* __restrict__ w2, const float* __restrict__ b2,
                       const float* __restrict__ w3, const float* __restrict__ b3,
                       float* __restrict__ out) {
  int g = blockIdx.x;
  int t = threadIdx.x;  // 64 threads
  __shared__ float m[64], s1[32], s2[16];
  int slo = lbound(s2g, 512, g);
  int shi = lbound(s2g, 512, g + 1);
  float acc = 0.f;
  for (int s = slo; s < shi; ++s)
    acc += ssum[(s << 6) + t] / fmaxf((float)cnt_sub[s], 1.f);
  m[t] = acc / fmaxf((float)(shi - slo), 1.f);
  __syncthreads();
  if (t < 32) {
    float a = b1[t];
    for (int i = 0; i < 64; ++i) a += m[i] * w1[i * 32 + t];
    s1[t] = a > 0.f ? a : expm1f(a);
  }
  __syncthreads();
  if (t < 16) {
    float a = b2[t];
    for (int i = 0; i < 32; ++i) a += s1[i] * w2[i * 16 + t];
    s2[t] = a > 0.f ? a : expm1f(a);
  }
  __syncthreads();
  if (t == 0) {
    float a = b3[0];
    for (int i = 0; i < 16; ++i) a += s2[i] * w3[i];
    out[g] = a;
  }
}

extern "C" void kernel_launch(void* const* d_in, const int* in_sizes, int n_in,
                              void* d_out, int out_size, void* d_ws, size_t ws_size,
                              hipStream_t stream) {
  (void)in_sizes; (void)n_in; (void)out_size; (void)ws_size;
  const float* x0 = (const float*)d_in[0];
  const int* ei = (const int*)d_in[1];
  const float* ea = (const float*)d_in[2];
  const int* n2s = (const int*)d_in[3];
  const int* s2g = (const int*)d_in[4];
  const float* W1_[3] = {(const float*)d_in[5], (const float*)d_in[11], (const float*)d_in[17]};
  const float* b1_[3] = {(const float*)d_in[6], (const float*)d_in[12], (const float*)d_in[18]};
  const float* W2_[3] = {(const float*)d_in[7], (const float*)d_in[13], (const float*)d_in[19]};
  const float* b2_[3] = {(const float*)d_in[8], (const float*)d_in[14], (const float*)d_in[20]};
  const float* rt_[3] = {(const float*)d_in[9], (const float*)d_in[15], (const float*)d_in[21]};
  const float* bs_[3] = {(const float*)d_in[10], (const float*)d_in[16], (const float*)d_in[22]};
  const float* fc1w = (const float*)d_in[23]; const float* fc1b = (const float*)d_in[24];
  const float* fc2w = (const float*)d_in[25]; const float* fc2b = (const float*)d_in[26];
  const float* fc3w = (const float*)d_in[27]; const float* fc3b = (const float*)d_in[28];
  float* out = (float*)d_out;

  const int* srcp = ei;
  const int* dstp = ei + E_EDGES;

  char* wsb = (char*)d_ws;
  size_t off = 0;
  auto alloc = [&](size_t bytes) {
    void* p = wsb + off;
    off += (bytes + 255) & ~(size_t)255;
    return p;
  };
  _Float16* Bsw0 = (_Float16*)alloc((size_t)PREP0 * 2);
  _Float16* Bsw1 = (_Float16*)alloc((size_t)PREP1 * 2);
  _Float16* Bsw2 = (_Float16*)alloc((size_t)PREP2 * 2);
  // zero region (contiguous, all sizes multiples of 256B)
  float* agg1 = (float*)alloc((size_t)NN * 32 * 4);
  float* agg2 = (float*)alloc((size_t)NN * 64 * 4);
  float* agg3 = (float*)alloc((size_t)NN * 64 * 4);
  float* ssum = (float*)alloc((size_t)512 * 64 * 4);
  int* cnt_sub = (int*)alloc((size_t)512 * 4);
  float* x1 = (float*)alloc((size_t)NN * 32 * 4);
  float* x2 = (float*)alloc((size_t)NN * 64 * 4);

  const int preptot = ZTOT + PREP0 + PREP1 + PREP2;
  prep_k<<<(preptot + 255) / 256, 256, 0, stream>>>(agg1, W2_[0], b2_[0], Bsw0,
                                                    W2_[1], b2_[1], Bsw1,
                                                    W2_[2], b2_[2], Bsw2);

  dim3 mg(E_EDGES / 256, 4);
  msg_mfma_k<16, 32><<<mg, 256, 0, stream>>>(x0, srcp, dstp, ea, W1_[0], b1_[0], Bsw0, agg1);
  fin_k<16, 32, false, true><<<NN / 8, 256, 0, stream>>>(x0, rt_[0], bs_[0], agg1, n2s, cnt_sub, ssum, x1);
  msg_mfma_k<32, 64><<<mg, 256, 0, stream>>>(x1, srcp, dstp, ea, W1_[1], b1_[1], Bsw1, agg2);
  fin_k<32, 64, false, false><<<NN / 4, 256, 0, stream>>>(x1, rt_[1], bs_[1], agg2, n2s, cnt_sub, ssum, x2);
  msg_mfma_k<64, 64><<<mg, 256, 0, stream>>>(x2, srcp, dstp, ea, W1_[2], b1_[2], Bsw2, agg3);
  fin_k<64, 64, true, false><<<NN / 4, 256, 0, stream>>>(x2, rt_[2], bs_[2], agg3, n2s, cnt_sub, ssum, nullptr);

  head_k<<<32, 64, 0, stream>>>(ssum, cnt_sub, s2g, fc1w, fc1b, fc2w, fc2b, fc3w, fc3b, out);
}

// Round 6
// 281.615 us; speedup vs baseline: 1.0937x; 1.0033x over previous
//
#include <hip/hip_runtime.h>

#define E_EDGES 32768
#define NN 8192
#define HID 128

typedef _Float16 half8 __attribute__((ext_vector_type(8)));
typedef _Float16 half4 __attribute__((ext_vector_type(4)));
typedef float f32x4 __attribute__((ext_vector_type(4)));

// ------- W2 -> f16 B-matrix, MFMA-fragment-linear layout -------------------
__device__ __forceinline__ void prep_one(int idx, int l2ci, int l2co,
                                         const float* __restrict__ W2,
                                         const float* __restrict__ b2,
                                         _Float16* __restrict__ out) {
  int CI = 1 << l2ci, CO = 1 << l2co;
  int Kmain = CI << 7;
  int j = idx & 7;
  int n = (idx >> 3) & (CO - 1);
  int kg = idx >> (3 + l2co);
  int k = kg * 8 + j;
  float v = 0.f;
  if (k < Kmain) {
    int hh = k >> l2ci, i = k & (CI - 1);
    v = W2[((hh << l2ci) + i) * CO + n];
  } else if (k < Kmain + CI) {
    v = b2[(k - Kmain) * CO + n];
  }
  out[idx] = (_Float16)v;
}

#define ZTOT (8192 * 32 + 8192 * 64 + 8192 * 64 + 512 * 64 + 512)
#define PREP0 (2176 * 32)
#define PREP1 (4224 * 64)
#define PREP2 (8320 * 64)

__global__ void prep_k(float* __restrict__ zr,
                       const float* __restrict__ W2a, const float* __restrict__ b2a, _Float16* __restrict__ oa,
                       const float* __restrict__ W2b, const float* __restrict__ b2b, _Float16* __restrict__ ob,
                       const float* __restrict__ W2c, const float* __restrict__ b2c, _Float16* __restrict__ oc) {
  int idx = blockIdx.x * 256 + threadIdx.x;
  if (idx < ZTOT) { zr[idx] = 0.f; return; }
  idx -= ZTOT;
  if (idx < PREP0) prep_one(idx, 4, 5, W2a, b2a, oa);
  else if (idx < PREP0 + PREP1) prep_one(idx - PREP0, 5, 6, W2b, b2b, ob);
  else if (idx < PREP0 + PREP1 + PREP2) prep_one(idx - PREP0 - PREP1, 6, 6, W2c, b2c, oc);
}

// ------- main fused kernel: edge MLP1 + Z@W2r GEMM (split-K=4) -------------
// ME=128 / depth-2 B prefetch / ~33 KB LDS / ~110 VGPR -> 4 blocks/CU
// (16 waves/CU, 50% occupancy) vs R5's hard 2-block cap. Barrier-free K-loop,
// A-side x in registers, he as b128 window reads, atomic scatter epilogue.
template <int CI, int CO>
__launch_bounds__(256, 4)
__global__ void msg_mfma_k(const float* __restrict__ xcur, const int* __restrict__ src,
                           const int* __restrict__ dst, const float* __restrict__ eattr,
                           const float* __restrict__ W1, const float* __restrict__ b1,
                           const _Float16* __restrict__ Bsw, float* __restrict__ agg) {
  constexpr int ME = 128;                      // edges per block
  constexpr int L2CI = (CI == 64) ? 6 : ((CI == 32) ? 5 : 4);
  constexpr int XSTR = CI + 8;
  constexpr int FC = CO / 16;
  constexpr int C4 = CI / 4;
  constexpr int L2C4 = L2CI - 2;
  constexpr int NV = (CI == 64) ? 2 : 1;       // x-fragment variants per lane
  constexpr int HS = 40;                       // he_t stride (80 B, 16B-aligned)
  constexpr int CW = CI / 4;                   // chunks per 8-h window
  constexpr int NP = CW / 2;                   // chunk-pairs per window

  __shared__ _Float16 he_t[ME * HS];           // [e][h-local(32)] transposed
  __shared__ _Float16 xs_s[ME * XSTR];         // [e][i]
  __shared__ float ea_s[ME * 5];
  __shared__ float W1s[5 * 32];
  __shared__ float b1s[32];
  __shared__ int src_s[ME];
  __shared__ int dst_s[ME];

  int t = threadIdx.x;
  int e0 = blockIdx.x * ME;
  int y = blockIdx.y;                          // split: h in [32y, 32y+32)
  int hbeg = y * 32;

  for (int j = t; j < ME * 5; j += 256) ea_s[j] = eattr[e0 * 5 + j];
  if (t < 5 * 32) W1s[t] = W1[(t >> 5) * HID + hbeg + (t & 31)];
  if (t < 32) b1s[t] = b1[hbeg + t];
  if (t < ME) { src_s[t] = src[e0 + t]; dst_s[t] = dst[e0 + t]; }
  __syncthreads();

  // edge MLP1 (this split's 32 h), written TRANSPOSED
  for (int j = t; j < 32 * ME; j += 256) {
    int hl = j >> 7, e = j & (ME - 1);
    float v = b1s[hl];
#pragma unroll
    for (int d = 0; d < 5; ++d) v += ea_s[e * 5 + d] * W1s[d * 32 + hl];
    he_t[e * HS + hl] = (_Float16)fmaxf(v, 0.f);
  }
  for (int j = t; j < ME * C4; j += 256) {
    int e = j >> L2C4, i4 = j & (C4 - 1);
    float4 v = ((const float4*)xcur)[src_s[e] * C4 + i4];
    half4 hq = {(_Float16)v.x, (_Float16)v.y, (_Float16)v.z, (_Float16)v.w};
    *(half4*)&xs_s[e * XSTR + i4 * 4] = hq;
  }
  __syncthreads();                             // last barrier

  int lane = t & 63;
  int w = t >> 6;
  int quad = lane >> 4, l15 = lane & 15;
  int hsel = (quad >> 1) & 1;                  // CI=16 h-select within chunk

  // loop-invariant per-lane A-side x fragments -> registers (2 row-frags/wave)
  half8 xreg[2][NV];
#pragma unroll
  for (int fr = 0; fr < 2; ++fr)
#pragma unroll
    for (int v = 0; v < NV; ++v)
      xreg[fr][v] = *(const half8*)&xs_s[(w * 32 + fr * 16 + l15) * XSTR +
                                         ((quad * 8 + v * 32) & (CI - 1))];

  int cbeg = y * CI;                           // chunks per split = CI
  int TC = CI + ((y == 3) ? 4 : 0);            // + b2/zero-pad tail chunks

  const half8* bsw8 = (const half8*)Bsw;
  int ib = quad * CO + l15;

  f32x4 acc[2][FC];
#pragma unroll
  for (int fr = 0; fr < 2; ++fr)
#pragma unroll
    for (int fc = 0; fc < FC; ++fc)
#pragma unroll
      for (int r = 0; r < 4; ++r) acc[fr][fc][r] = 0.f;

  half8 breg[2][FC];
#pragma unroll
  for (int p = 0; p < 2; ++p)
#pragma unroll
    for (int fc = 0; fc < FC; ++fc)
      breg[p][fc] = bsw8[(cbeg + p) * 4 * CO + ib + fc * 16];

  for (int win = 0; win < 4; ++win) {
    half8 hreg[2];
#pragma unroll
    for (int fr = 0; fr < 2; ++fr)
      hreg[fr] = *(const half8*)&he_t[(w * 32 + fr * 16 + l15) * HS + win * 8];
    for (int cl2 = 0; cl2 < NP; ++cl2) {
#pragma unroll
      for (int p = 0; p < 2; ++p) {
        int cl = win * CW + cl2 * 2 + p;       // chunk-local 0..CI-1
        int vi = (CI == 64) ? p : 0;
        half8 a[2];
#pragma unroll
        for (int fr = 0; fr < 2; ++fr) {
          _Float16 hv;
          if (CI == 16)      hv = hreg[fr][2 * (cl2 * 2 + p) + hsel];
          else if (CI == 32) hv = hreg[fr][cl2 * 2 + p];
          else               hv = hreg[fr][cl2];
          half8 hb = {hv, hv, hv, hv, hv, hv, hv, hv};
          a[fr] = xreg[fr][vi] * hb;
        }
#pragma unroll
        for (int fc = 0; fc < FC; ++fc) {
#pragma unroll
          for (int fr = 0; fr < 2; ++fr)
            acc[fr][fc] = __builtin_amdgcn_mfma_f32_16x16x32_f16(a[fr], breg[p][fc], acc[fr][fc], 0, 0, 0);
        }
        int cn = cl + 2;
        if (cn >= TC) cn = TC - 1;             // clamped branch-free prefetch
#pragma unroll
        for (int fc = 0; fc < FC; ++fc)
          breg[p][fc] = bsw8[(cbeg + cn) * 4 * CO + ib + fc * 16];
      }
    }
  }

  // b2 tail (4 chunks, he == 1), only on split 3; breg rotation continues
  if (y == 3) {
#pragma unroll
    for (int j = 0; j < 4; ++j) {
      int cl = CI + j;
      int p = j & 1;                           // CI even -> cl&1 == j&1
      int vi = (CI == 64) ? p : 0;
#pragma unroll
      for (int fc = 0; fc < FC; ++fc) {
#pragma unroll
        for (int fr = 0; fr < 2; ++fr)
          acc[fr][fc] = __builtin_amdgcn_mfma_f32_16x16x32_f16(xreg[fr][vi], breg[p][fc], acc[fr][fc], 0, 0, 0);
      }
      int cn = cl + 2;
      if (cn >= TC) cn = TC - 1;
#pragma unroll
      for (int fc = 0; fc < FC; ++fc)
        breg[p][fc] = bsw8[(cbeg + cn) * 4 * CO + ib + fc * 16];
    }
  }

  // epilogue: scatter partials into agg via device atomics.
  // C/D layout: row(e_local)=quad*4+r, col(o)=l15.
#pragma unroll
  for (int fr = 0; fr < 2; ++fr)
#pragma unroll
    for (int r = 0; r < 4; ++r) {
      int el = w * 32 + fr * 16 + quad * 4 + r;
      int d = dst_s[el];
      float* base = agg + (size_t)d * CO + l15;
#pragma unroll
      for (int fc = 0; fc < FC; ++fc)
        atomicAdd(base + fc * 16, acc[fr][fc][r]);
    }
}

// ------- finish: ELU(agg + x@root + bias); fin1 counts, fin3 pools ---------
template <int CI, int CO, bool POOL, bool CNT>
__global__ void fin_k(const float* __restrict__ xcur, const float* __restrict__ root,
                      const float* __restrict__ bias, const float* __restrict__ agg,
                      const int* __restrict__ n2s, int* __restrict__ cnt_sub,
                      float* __restrict__ ssum, float* __restrict__ xnext) {
  constexpr int NB = 256 / CO;
  __shared__ float xs[NB * CI];
  int t = threadIdx.x;
  int n0 = blockIdx.x * NB;
  for (int j = t; j < NB * CI; j += 256) xs[j] = xcur[n0 * CI + j];
  __syncthreads();
  int nl = t / CO, o = t & (CO - 1);
  int n = n0 + nl;
  float a = bias[o] + agg[n * CO + o];
#pragma unroll
  for (int i = 0; i < CI; ++i) a += xs[nl * CI + i] * root[i * CO + o];
  float r = a > 0.f ? a : expm1f(a);
  if (CNT && o == 0) atomicAdd(&cnt_sub[n2s[n]], 1);
  if (POOL) atomicAdd(&ssum[(n2s[n] << 6) + o], r);
  else xnext[n * CO + o] = r;
}

// ------- head: per-graph pool (32 blocks x 64 thr) + MLP -------------------
__device__ __forceinline__ int lbound(const int* __restrict__ a, int n, int v) {
  int lo = 0, hi = n;
  while (lo < hi) { int m = (lo + hi) >> 1; if (a[m] < v) lo = m + 1; else hi = m; }
  return lo;
}

__global__ void head_k(const float* __restrict__ ssum, const int* __restrict__ cnt_sub,
                       const int* __restrict__ s2g,
                       const float* __restrict__ w1, const float* __restrict__ b1,
                       const float* __restrict__ w2, const float* __restrict__ b2,
                       const float* __restrict__ w3, const float* __restrict__ b3,
                       float* __restrict__ out) {
  int g = blockIdx.x;
  int t = threadIdx.x;  // 64 threads
  __shared__ float m[64], s1[32], s2[16];
  int slo = lbound(s2g, 512, g);
  int shi = lbound(s2g, 512, g + 1);
  float acc = 0.f;
  for (int s = slo; s < shi; ++s)
    acc += ssum[(s << 6) + t] / fmaxf((float)cnt_sub[s], 1.f);
  m[t] = acc / fmaxf((float)(shi - slo), 1.f);
  __syncthreads();
  if (t < 32) {
    float a = b1[t];
    for (int i = 0; i < 64; ++i) a += m[i] * w1[i * 32 + t];
    s1[t] = a > 0.f ? a : expm1f(a);
  }
  __syncthreads();
  if (t < 16) {
    float a = b2[t];
    for (int i = 0; i < 32; ++i) a += s1[i] * w2[i * 16 + t];
    s2[t] = a > 0.f ? a : expm1f(a);
  }
  __syncthreads();
  if (t == 0) {
    float a = b3[0];
    for (int i = 0; i < 16; ++i) a += s2[i] * w3[i];
    out[g] = a;
  }
}

extern "C" void kernel_launch(void* const* d_in, const int* in_sizes, int n_in,
                              void* d_out, int out_size, void* d_ws, size_t ws_size,
                              hipStream_t stream) {
  (void)in_sizes; (void)n_in; (void)out_size; (void)ws_size;
  const float* x0 = (const float*)d_in[0];
  const int* ei = (const int*)d_in[1];
  const float* ea = (const float*)d_in[2];
  const int* n2s = (const int*)d_in[3];
  const int* s2g = (const int*)d_in[4];
  const float* W1_[3] = {(const float*)d_in[5], (const float*)d_in[11], (const float*)d_in[17]};
  const float* b1_[3] = {(const float*)d_in[6], (const float*)d_in[12], (const float*)d_in[18]};
  const float* W2_[3] = {(const float*)d_in[7], (const float*)d_in[13], (const float*)d_in[19]};
  const float* b2_[3] = {(const float*)d_in[8], (const float*)d_in[14], (const float*)d_in[20]};
  const float* rt_[3] = {(const float*)d_in[9], (const float*)d_in[15], (const float*)d_in[21]};
  const float* bs_[3] = {(const float*)d_in[10], (const float*)d_in[16], (const float*)d_in[22]};
  const float* fc1w = (const float*)d_in[23]; const float* fc1b = (const float*)d_in[24];
  const float* fc2w = (const float*)d_in[25]; const float* fc2b = (const float*)d_in[26];
  const float* fc3w = (const float*)d_in[27]; const float* fc3b = (const float*)d_in[28];
  float* out = (float*)d_out;

  const int* srcp = ei;
  const int* dstp = ei + E_EDGES;

  char* wsb = (char*)d_ws;
  size_t off = 0;
  auto alloc = [&](size_t bytes) {
    void* p = wsb + off;
    off += (bytes + 255) & ~(size_t)255;
    return p;
  };
  _Float16* Bsw0 = (_Float16*)alloc((size_t)PREP0 * 2);
  _Float16* Bsw1 = (_Float16*)alloc((size_t)PREP1 * 2);
  _Float16* Bsw2 = (_Float16*)alloc((size_t)PREP2 * 2);
  // zero region (contiguous, all sizes multiples of 256B)
  float* agg1 = (float*)alloc((size_t)NN * 32 * 4);
  float* agg2 = (float*)alloc((size_t)NN * 64 * 4);
  float* agg3 = (float*)alloc((size_t)NN * 64 * 4);
  float* ssum = (float*)alloc((size_t)512 * 64 * 4);
  int* cnt_sub = (int*)alloc((size_t)512 * 4);
  float* x1 = (float*)alloc((size_t)NN * 32 * 4);
  float* x2 = (float*)alloc((size_t)NN * 64 * 4);

  const int preptot = ZTOT + PREP0 + PREP1 + PREP2;
  prep_k<<<(preptot + 255) / 256, 256, 0, stream>>>(agg1, W2_[0], b2_[0], Bsw0,
                                                    W2_[1], b2_[1], Bsw1,
                                                    W2_[2], b2_[2], Bsw2);

  dim3 mg(E_EDGES / 128, 4);
  msg_mfma_k<16, 32><<<mg, 256, 0, stream>>>(x0, srcp, dstp, ea, W1_[0], b1_[0], Bsw0, agg1);
  fin_k<16, 32, false, true><<<NN / 8, 256, 0, stream>>>(x0, rt_[0], bs_[0], agg1, n2s, cnt_sub, ssum, x1);
  msg_mfma_k<32, 64><<<mg, 256, 0, stream>>>(x1, srcp, dstp, ea, W1_[1], b1_[1], Bsw1, agg2);
  fin_k<32, 64, false, false><<<NN / 4, 256, 0, stream>>>(x1, rt_[1], bs_[1], agg2, n2s, cnt_sub, ssum, x2);
  msg_mfma_k<64, 64><<<mg, 256, 0, stream>>>(x2, srcp, dstp, ea, W1_[2], b1_[2], Bsw2, agg3);
  fin_k<64, 64, true, false><<<NN / 4, 256, 0, stream>>>(x2, rt_[2], bs_[2], agg3, n2s, cnt_sub, ssum, nullptr);

  head_k<<<32, 64, 0, stream>>>(ssum, cnt_sub, s2g, fc1w, fc1b, fc2w, fc2b, fc3w, fc3b, out);
}